// Round 5
// baseline (403.999 us; speedup 1.0000x reference)
//
#include <hip/hip_runtime.h>

#define EMBED  256
#define NGRAPH 256
#define CH     128   // nodes per K1 block
#define MAXG   4     // partial-row slots per wave
#define NB3    64    // nodes per K3 block (16 per wave)

typedef __attribute__((ext_vector_type(4))) float f4;

// ---------------------------------------------------------------------------
// K1: per-wave partial segment sums -> workspace. NO atomics, NO occupancy
// bound (let the allocator keep 8 f4 load destinations live -> 8 loads in
// flight per wave). Block = 4 waves over a 128-node chunk; wave q owns nodes
// q, q+4, ...; 64 lanes x f4 = 1 KB coalesced per node row.
// ---------------------------------------------------------------------------
__global__ void k1_partial(
    const float* __restrict__ x, const int* __restrict__ batch,
    f4* __restrict__ part, int* __restrict__ pgid, int nNodes) {
  __shared__ int sb[CH];
  const int blk   = blockIdx.x;
  const int start = blk * CH;
  const int cnt   = min(CH, nNodes - start);
  const int t     = threadIdx.x;
  if (t < cnt) sb[t] = batch[start + t];
  __syncthreads();

  const int q    = t >> 6;
  const int lane = t & 63;
  const f4* xp   = (const f4*)x + (size_t)start * 64 + lane;
  const int slot0 = (blk * 4 + q) * MAXG;

  f4 acc = (f4){0.f, 0.f, 0.f, 0.f};

  if (cnt == CH && sb[0] == sb[CH - 1]) {
    // ---- fast path: whole chunk is one graph; keep 8 loads in flight ----
#pragma unroll
    for (int k = 0; k < 32; k += 8) {
      f4 v0 = xp[(size_t)((k + 0) * 4 + q) * 64];
      f4 v1 = xp[(size_t)((k + 1) * 4 + q) * 64];
      f4 v2 = xp[(size_t)((k + 2) * 4 + q) * 64];
      f4 v3 = xp[(size_t)((k + 3) * 4 + q) * 64];
      f4 v4 = xp[(size_t)((k + 4) * 4 + q) * 64];
      f4 v5 = xp[(size_t)((k + 5) * 4 + q) * 64];
      f4 v6 = xp[(size_t)((k + 6) * 4 + q) * 64];
      f4 v7 = xp[(size_t)((k + 7) * 4 + q) * 64];
      acc += (v0 + v1) + (v2 + v3) + ((v4 + v5) + (v6 + v7));
    }
    part[(size_t)slot0 * 64 + lane] = acc;
    if (lane == 0) {
      pgid[slot0 + 0] = sb[0];
      pgid[slot0 + 1] = -1; pgid[slot0 + 2] = -1; pgid[slot0 + 3] = -1;
    }
  } else {
    // ---- slow path: boundary / tail chunk ----
    int m = 0, cur = -1;
    for (int i = q; i < cnt; i += 4) {
      const int g = sb[i];                 // wave-uniform
      if (g != cur) {
        if (cur >= 0 && m < MAXG) {
          part[(size_t)(slot0 + m) * 64 + lane] = acc;
          if (lane == 0) pgid[slot0 + m] = cur;
          m++;
        }
        acc = (f4){0.f, 0.f, 0.f, 0.f};
        cur = g;
      }
      acc += xp[(size_t)i * 64];
    }
    if (cur >= 0 && m < MAXG) {
      part[(size_t)(slot0 + m) * 64 + lane] = acc;
      if (lane == 0) pgid[slot0 + m] = cur;
      m++;
    }
    if (lane == 0)
      for (int s = m; s < MAXG; ++s) pgid[slot0 + s] = -1;
  }
}

// ---------------------------------------------------------------------------
// K2: one block per graph. Reduce the graph's ~26 L2-hot partial rows,
// mean, two 256x256 matvecs (thread t -> column t), write the graph row.
// ---------------------------------------------------------------------------
__global__ __launch_bounds__(256) void k2_mlp(
    const int* __restrict__ batch,
    const f4* __restrict__ part, const int* __restrict__ pgid,
    const float* __restrict__ in_w, const float* __restrict__ in_b,
    const float* __restrict__ out_w, const float* __restrict__ out_b,
    float* __restrict__ rows, int nNodes) {
  const int g = blockIdx.x;
  const int t = threadIdx.x;

  int n0, n1;
  { int a = 0, b = nNodes;
    while (a < b) { int m = (a + b) >> 1; (batch[m] <  g) ? (a = m + 1) : (b = m); }
    n0 = a; }
  { int a = n0, b = nNodes;
    while (a < b) { int m = (a + b) >> 1; (batch[m] <= g) ? (a = m + 1) : (b = m); }
    n1 = a; }
  const int cnt = n1 - n0;

  float s = 0.f;
  if (cnt > 0) {
    const int b0 = n0 / CH, b1 = (n1 - 1) / CH;
    const float* pf = (const float*)part;
    for (int r = b0 * 4 * MAXG; r < (b1 + 1) * 4 * MAXG; ++r) {
      if (pgid[r] == g) s += pf[(size_t)r * EMBED + t];
    }
  }

  __shared__ float sg[EMBED];
  __shared__ float sv[EMBED];
  sg[t] = s / fmaxf((float)cnt, 1.0f);
  __syncthreads();

  float acc = in_b[2 * EMBED + t];
  const float4* wrow = (const float4*)(in_w + (size_t)(2 * EMBED + t) * EMBED);
#pragma unroll 8
  for (int k4 = 0; k4 < EMBED / 4; ++k4) {
    const float4 w = wrow[k4];
    const int k = k4 * 4;
    acc += sg[k] * w.x + sg[k + 1] * w.y + sg[k + 2] * w.z + sg[k + 3] * w.w;
  }
  sv[t] = acc;
  __syncthreads();

  float acc2 = out_b[t];
  const float4* w2row = (const float4*)(out_w + (size_t)t * EMBED);
#pragma unroll 8
  for (int k4 = 0; k4 < EMBED / 4; ++k4) {
    const float4 w = w2row[k4];
    const int k = k4 * 4;
    acc2 += sv[k] * w.x + sv[k + 1] * w.y + sv[k + 2] * w.z + sv[k + 3] * w.w;
  }
  rows[(size_t)g * EMBED + t] = acc2;
}

// ---------------------------------------------------------------------------
// K3: out[n] = rows[batch[n]]. 64 nodes per block, 16 per wave -> 16 KB of
// stores per wave amortizes the wave lifecycle. Graph row held in registers
// across the (rare) wave-uniform g==prevg run; nt stores (out never read).
// ---------------------------------------------------------------------------
__global__ __launch_bounds__(256) void k3_gather(
    const float* __restrict__ rows, const int* __restrict__ batch,
    f4* __restrict__ out, int nNodes) {
  const int q    = threadIdx.x >> 6;
  const int lane = threadIdx.x & 63;
  const int base = blockIdx.x * NB3 + q * (NB3 / 4);
  const int end  = min(base + NB3 / 4, nNodes);
  int prevg = -1;
  f4 v = (f4){0.f, 0.f, 0.f, 0.f};
  for (int n = base; n < end; ++n) {
    const int g = batch[n];                    // wave-uniform, L1-hot
    if (g != prevg) { v = ((const f4*)rows)[g * 64 + lane]; prevg = g; }
    __builtin_nontemporal_store(v, out + (size_t)n * 64 + lane);
  }
}

extern "C" void kernel_launch(void* const* d_in, const int* in_sizes, int n_in,
                              void* d_out, int out_size, void* d_ws, size_t ws_size,
                              hipStream_t stream) {
  const float* x     = (const float*)d_in[0];
  const float* in_w  = (const float*)d_in[1];
  const float* in_b  = (const float*)d_in[2];
  const float* out_w = (const float*)d_in[3];
  const float* out_b = (const float*)d_in[4];
  const int*   batch = (const int*)d_in[5];
  const int nNodes = in_sizes[5];

  const int nb = (nNodes + CH - 1) / CH;
  const int nSlots = nb * 4 * MAXG;

  f4*    part = (f4*)d_ws;                             // [nSlots][64]
  float* rows = (float*)(part + (size_t)nSlots * 64);  // [NGRAPH][EMBED]
  int*   pgid = (int*)(rows + (size_t)NGRAPH * EMBED); // [nSlots]

  k1_partial<<<nb, 256, 0, stream>>>(x, batch, part, pgid, nNodes);

  k2_mlp<<<NGRAPH, 256, 0, stream>>>(batch, part, pgid, in_w, in_b,
                                     out_w, out_b, rows, nNodes);

  const int nb3 = (nNodes + NB3 - 1) / NB3;
  k3_gather<<<nb3, 256, 0, stream>>>(rows, batch, (f4*)d_out, nNodes);
}

// Round 6
// 389.504 us; speedup vs baseline: 1.0372x; 1.0372x over previous
//
#include <hip/hip_runtime.h>

#define EMBED  256
#define NGRAPH 256
#define CH     128   // nodes per K1 block
#define MAXG   4     // partial-row slots per wave
#define NB3    64    // nodes per K3 block (16 per wave)

typedef __attribute__((ext_vector_type(4))) float f4;

// ---------------------------------------------------------------------------
// K1 (R4 version, verbatim): per-wave partial segment sums -> workspace.
// __launch_bounds__(256,8): 64-VGPR cap still fits 8 f4 load dests + voffsets
// + acc (~55 VGPRs) -> 8 loads in flight AND 8 blocks/CU occupancy.
// ---------------------------------------------------------------------------
__global__ __launch_bounds__(256, 8) void k1_partial(
    const float* __restrict__ x, const int* __restrict__ batch,
    f4* __restrict__ part, int* __restrict__ pgid, int nNodes) {
  __shared__ int sb[CH];
  const int blk   = blockIdx.x;
  const int start = blk * CH;
  const int cnt   = min(CH, nNodes - start);
  const int t     = threadIdx.x;
  if (t < cnt) sb[t] = batch[start + t];
  __syncthreads();

  const int q    = t >> 6;
  const int lane = t & 63;
  const f4* xp   = (const f4*)x + (size_t)start * 64 + lane;
  const int slot0 = (blk * 4 + q) * MAXG;

  f4 acc = (f4){0.f, 0.f, 0.f, 0.f};

  if (cnt == CH && sb[0] == sb[CH - 1]) {
    // ---- fast path: whole chunk is one graph; 8 loads in flight ----
#pragma unroll
    for (int k = 0; k < 32; k += 8) {
      f4 v0 = __builtin_nontemporal_load(xp + (size_t)((k + 0) * 4 + q) * 64);
      f4 v1 = __builtin_nontemporal_load(xp + (size_t)((k + 1) * 4 + q) * 64);
      f4 v2 = __builtin_nontemporal_load(xp + (size_t)((k + 2) * 4 + q) * 64);
      f4 v3 = __builtin_nontemporal_load(xp + (size_t)((k + 3) * 4 + q) * 64);
      f4 v4 = __builtin_nontemporal_load(xp + (size_t)((k + 4) * 4 + q) * 64);
      f4 v5 = __builtin_nontemporal_load(xp + (size_t)((k + 5) * 4 + q) * 64);
      f4 v6 = __builtin_nontemporal_load(xp + (size_t)((k + 6) * 4 + q) * 64);
      f4 v7 = __builtin_nontemporal_load(xp + (size_t)((k + 7) * 4 + q) * 64);
      acc += (v0 + v1) + (v2 + v3) + ((v4 + v5) + (v6 + v7));
    }
    part[(size_t)slot0 * 64 + lane] = acc;
    if (lane == 0) {
      pgid[slot0 + 0] = sb[0];
      pgid[slot0 + 1] = -1; pgid[slot0 + 2] = -1; pgid[slot0 + 3] = -1;
    }
  } else {
    // ---- slow path: boundary / tail chunk ----
    int m = 0, cur = -1;
    for (int i = q; i < cnt; i += 4) {
      const int g = sb[i];                 // wave-uniform
      if (g != cur) {
        if (cur >= 0 && m < MAXG) {
          part[(size_t)(slot0 + m) * 64 + lane] = acc;
          if (lane == 0) pgid[slot0 + m] = cur;
          m++;
        }
        acc = (f4){0.f, 0.f, 0.f, 0.f};
        cur = g;
      }
      acc += __builtin_nontemporal_load(xp + (size_t)i * 64);
    }
    if (cur >= 0 && m < MAXG) {
      part[(size_t)(slot0 + m) * 64 + lane] = acc;
      if (lane == 0) pgid[slot0 + m] = cur;
      m++;
    }
    if (lane == 0)
      for (int s = m; s < MAXG; ++s) pgid[slot0 + s] = -1;
  }
}

// ---------------------------------------------------------------------------
// K2: one block per graph. Reduce the graph's ~26 L2-hot partial rows,
// mean, two 256x256 matvecs (thread t -> column t), write the graph row.
// ---------------------------------------------------------------------------
__global__ __launch_bounds__(256) void k2_mlp(
    const int* __restrict__ batch,
    const f4* __restrict__ part, const int* __restrict__ pgid,
    const float* __restrict__ in_w, const float* __restrict__ in_b,
    const float* __restrict__ out_w, const float* __restrict__ out_b,
    float* __restrict__ rows, int nNodes) {
  const int g = blockIdx.x;
  const int t = threadIdx.x;

  int n0, n1;
  { int a = 0, b = nNodes;
    while (a < b) { int m = (a + b) >> 1; (batch[m] <  g) ? (a = m + 1) : (b = m); }
    n0 = a; }
  { int a = n0, b = nNodes;
    while (a < b) { int m = (a + b) >> 1; (batch[m] <= g) ? (a = m + 1) : (b = m); }
    n1 = a; }
  const int cnt = n1 - n0;

  float s = 0.f;
  if (cnt > 0) {
    const int b0 = n0 / CH, b1 = (n1 - 1) / CH;
    const float* pf = (const float*)part;
    for (int r = b0 * 4 * MAXG; r < (b1 + 1) * 4 * MAXG; ++r) {
      if (pgid[r] == g) s += pf[(size_t)r * EMBED + t];
    }
  }

  __shared__ float sg[EMBED];
  __shared__ float sv[EMBED];
  sg[t] = s / fmaxf((float)cnt, 1.0f);
  __syncthreads();

  float acc = in_b[2 * EMBED + t];
  const float4* wrow = (const float4*)(in_w + (size_t)(2 * EMBED + t) * EMBED);
#pragma unroll 8
  for (int k4 = 0; k4 < EMBED / 4; ++k4) {
    const float4 w = wrow[k4];
    const int k = k4 * 4;
    acc += sg[k] * w.x + sg[k + 1] * w.y + sg[k + 2] * w.z + sg[k + 3] * w.w;
  }
  sv[t] = acc;
  __syncthreads();

  float acc2 = out_b[t];
  const float4* w2row = (const float4*)(out_w + (size_t)t * EMBED);
#pragma unroll 8
  for (int k4 = 0; k4 < EMBED / 4; ++k4) {
    const float4 w = w2row[k4];
    const int k = k4 * 4;
    acc2 += sv[k] * w.x + sv[k + 1] * w.y + sv[k + 2] * w.z + sv[k + 3] * w.w;
  }
  rows[(size_t)g * EMBED + t] = acc2;
}

// ---------------------------------------------------------------------------
// K3 (R5 version, verbatim): 64 nodes per block, 16 per wave -> 3125 blocks
// (avoids CP dispatch-rate limit of 50000 tiny blocks). Row held in regs
// across the wave-uniform g==prevg run; nt stores (out never re-read).
// ---------------------------------------------------------------------------
__global__ __launch_bounds__(256) void k3_gather(
    const float* __restrict__ rows, const int* __restrict__ batch,
    f4* __restrict__ out, int nNodes) {
  const int q    = threadIdx.x >> 6;
  const int lane = threadIdx.x & 63;
  const int base = blockIdx.x * NB3 + q * (NB3 / 4);
  const int end  = min(base + NB3 / 4, nNodes);
  int prevg = -1;
  f4 v = (f4){0.f, 0.f, 0.f, 0.f};
  for (int n = base; n < end; ++n) {
    const int g = batch[n];                    // wave-uniform, L1-hot
    if (g != prevg) { v = ((const f4*)rows)[g * 64 + lane]; prevg = g; }
    __builtin_nontemporal_store(v, out + (size_t)n * 64 + lane);
  }
}

extern "C" void kernel_launch(void* const* d_in, const int* in_sizes, int n_in,
                              void* d_out, int out_size, void* d_ws, size_t ws_size,
                              hipStream_t stream) {
  const float* x     = (const float*)d_in[0];
  const float* in_w  = (const float*)d_in[1];
  const float* in_b  = (const float*)d_in[2];
  const float* out_w = (const float*)d_in[3];
  const float* out_b = (const float*)d_in[4];
  const int*   batch = (const int*)d_in[5];
  const int nNodes = in_sizes[5];

  const int nb = (nNodes + CH - 1) / CH;
  const int nSlots = nb * 4 * MAXG;

  f4*    part = (f4*)d_ws;                             // [nSlots][64]
  float* rows = (float*)(part + (size_t)nSlots * 64);  // [NGRAPH][EMBED]
  int*   pgid = (int*)(rows + (size_t)NGRAPH * EMBED); // [nSlots]

  k1_partial<<<nb, 256, 0, stream>>>(x, batch, part, pgid, nNodes);

  k2_mlp<<<NGRAPH, 256, 0, stream>>>(batch, part, pgid, in_w, in_b,
                                     out_w, out_b, rows, nNodes);

  const int nb3 = (nNodes + NB3 - 1) / NB3;
  k3_gather<<<nb3, 256, 0, stream>>>(rows, batch, (f4*)d_out, nNodes);
}